// Round 11
// baseline (309.206 us; speedup 1.0000x reference)
//
#include <hip/hip_runtime.h>

#define D_IN 256
#define D_HID 512
#define D_OUT 256
#define LN_EPS 1e-5f
#define SCAN_B 512   // chunk size; readers use bases[i>>9]+offs[i]

typedef __attribute__((ext_vector_type(8))) short bf16x8;
typedef __attribute__((ext_vector_type(4))) float f32x4;

__device__ __forceinline__ ushort f2bf(float x) {
    union { float f; unsigned u; } c; c.f = x;
    unsigned r = c.u + 0x7FFFu + ((c.u >> 16) & 1u);   // round-to-nearest-even
    return (ushort)(r >> 16);
}
__device__ __forceinline__ float bf2f(unsigned b) {
    union { unsigned u; float f; } c; c.u = b << 16;
    return c.f;
}

// ---------------------------------------------------------------------------
// prep: cvt v->bf16 | cvt w1,w2->bf16 PACKED in MFMA-fragment order |
//       edge hist+rank (cnt pre-zeroed by hipMemsetAsync)
// ---------------------------------------------------------------------------
__global__ void prep_kernel(const float* __restrict__ v, const float* __restrict__ w1,
                            const float* __restrict__ w2, ushort* __restrict__ vb,
                            ushort* __restrict__ w1p, ushort* __restrict__ w2p,
                            const int* __restrict__ dst, int* __restrict__ rank,
                            int* __restrict__ cnt, int n4v, int E,
                            int bv, int bw) {
    int b = blockIdx.x, t = threadIdx.x;
    if (b < bv) {
        int i = b * 256 + t;
        if (i < n4v) {
            float4 x = ((const float4*)v)[i];
            ((ushort4*)vb)[i] = make_ushort4(f2bf(x.x), f2bf(x.y), f2bf(x.z), f2bf(x.w));
        }
    } else if (b < bv + bw) {
        int j = (b - bv) * 256 + t;     // 0..65535 float4s (w1: first 32768)
        if (j < 32768) {                // w1: [512][256] fp32
            int f = j * 4;
            int row = f >> 8, col = f & 255;
            float4 x = ((const float4*)w1)[j];
            int rb = row >> 4, fr = row & 15;
            int kb32 = col >> 5, q = (col & 31) >> 3, e = col & 7;
            int chunk = (kb32 * 32 + rb) * 64 + q * 16 + fr;
            *(ushort4*)(w1p + chunk * 8 + e) =
                make_ushort4(f2bf(x.x), f2bf(x.y), f2bf(x.z), f2bf(x.w));
        } else {                        // w2: [256][512] fp32
            int k = j - 32768;
            int f = k * 4;
            int row = f >> 9, col = f & 511;
            float4 x = ((const float4*)w2)[k];
            int rb = row >> 4, fr = row & 15;
            int kb32 = col >> 5, q = (col & 31) >> 3, e = col & 7;
            int chunk = (kb32 * 16 + rb) * 64 + q * 16 + fr;
            *(ushort4*)(w2p + chunk * 8 + e) =
                make_ushort4(f2bf(x.x), f2bf(x.y), f2bf(x.z), f2bf(x.w));
        }
    } else {
        int e = (b - bv - bw) * 256 + t;
        if (e < E) rank[e] = atomicAdd(&cnt[dst[e]], 1);
    }
}

// ---------------------------------------------------------------------------
// merged CSR scan (replaces scan1+scan3): per-chunk exclusive scan -> offs
// (chunk-local, incl. index N), chunk totals -> bsum; the LAST-arriving block
// (one atomicAdd on done, NO spinning -> deadlock-free) scans the nb chunk
// totals into bases[]. Readers use  global_off(i) = bases[i>>9] + offs[i].
// Requires nb <= SCAN_B (N <= 262143).
// ---------------------------------------------------------------------------
__global__ __launch_bounds__(SCAN_B) void scan_kernel(
    const int* __restrict__ cnt, int* __restrict__ offs,
    int* __restrict__ bsum, int* __restrict__ bases,
    int* __restrict__ done, int n, int nb) {
    __shared__ int s[SCAN_B];
    __shared__ int amLast;
    int t = threadIdx.x, b = blockIdx.x;
    int i = b * SCAN_B + t;
    int x = (i < n) ? cnt[i] : 0;
    s[t] = x;
    __syncthreads();
    for (int o = 1; o < SCAN_B; o <<= 1) {
        int u = (t >= o) ? s[t - o] : 0;
        __syncthreads();
        s[t] += u;
        __syncthreads();
    }
    if (i <= n) offs[i] = s[t] - x;       // i==n gets chunk-local inclusive total
    if (t == SCAN_B - 1) bsum[b] = s[t];
    __threadfence();                       // release bsum/offs device-wide
    __syncthreads();
    if (t == 0) amLast = (atomicAdd(done, 1) == nb - 1);
    __syncthreads();
    if (amLast) {
        __threadfence();                   // acquire other blocks' bsum
        int y = (t < nb) ? bsum[t] : 0;
        s[t] = y;
        __syncthreads();
        for (int o = 1; o < SCAN_B; o <<= 1) {
            int u = (t >= o) ? s[t - o] : 0;
            __syncthreads();
            s[t] += u;
            __syncthreads();
        }
        if (t < nb) bases[t] = s[t] - y;   // exclusive chunk bases
    }
}

// counting-sort fill, NO atomics: slot = bases[d>>9] + offs[d] + rank[e]
__global__ void fill_kernel(const int* __restrict__ src, const int* __restrict__ dst,
                            const float* __restrict__ ew, const int* __restrict__ rank,
                            const int* __restrict__ offs, const int* __restrict__ bases,
                            int2* __restrict__ perm, int E) {
    int e = blockIdx.x * 256 + threadIdx.x;
    if (e >= E) return;
    int d = dst[e];
    int p = bases[d >> 9] + offs[d] + rank[e];
    perm[p] = make_int2(src[e], __float_as_int(ew[e]));
}

// ---------------------------------------------------------------------------
// agg_bf16[n] = bf16( eps*vb[n] + sum_{e:dst=n} w_e * vb[src_e] )
// one wave/node, 12.5k blocks for TLP (R6: 59.6us, occ 60%).
// ---------------------------------------------------------------------------
__global__ __launch_bounds__(256) void aggregate_kernel(
    const ushort* __restrict__ vb, const float* __restrict__ eps_p,
    const int* __restrict__ offs, const int* __restrict__ bases,
    const int2* __restrict__ perm, ushort* __restrict__ aggb, int N) {
    int node = blockIdx.x * 4 + (threadIdx.x >> 6);
    if (node >= N) return;
    int lane = threadIdx.x & 63;
    int beg = bases[node >> 9] + offs[node];
    int m1 = node + 1;
    int end = bases[m1 >> 9] + offs[m1];
    float a0 = 0.f, a1 = 0.f, a2 = 0.f, a3 = 0.f;
    float c0 = 0.f, c1 = 0.f, c2 = 0.f, c3 = 0.f;

    int i = beg;
    for (; i + 8 <= end; i += 8) {
        int2 p0 = perm[i + 0], p1 = perm[i + 1], p2 = perm[i + 2], p3 = perm[i + 3];
        int2 p4 = perm[i + 4], p5 = perm[i + 5], p6 = perm[i + 6], p7 = perm[i + 7];
        float w0 = __int_as_float(p0.y), w1 = __int_as_float(p1.y);
        float w2 = __int_as_float(p2.y), w3 = __int_as_float(p3.y);
        float w4 = __int_as_float(p4.y), w5 = __int_as_float(p5.y);
        float w6 = __int_as_float(p6.y), w7 = __int_as_float(p7.y);
        ushort4 r0 = ((const ushort4*)(vb + (size_t)p0.x * D_IN))[lane];
        ushort4 r1 = ((const ushort4*)(vb + (size_t)p1.x * D_IN))[lane];
        ushort4 r2 = ((const ushort4*)(vb + (size_t)p2.x * D_IN))[lane];
        ushort4 r3 = ((const ushort4*)(vb + (size_t)p3.x * D_IN))[lane];
        ushort4 r4 = ((const ushort4*)(vb + (size_t)p4.x * D_IN))[lane];
        ushort4 r5 = ((const ushort4*)(vb + (size_t)p5.x * D_IN))[lane];
        ushort4 r6 = ((const ushort4*)(vb + (size_t)p6.x * D_IN))[lane];
        ushort4 r7 = ((const ushort4*)(vb + (size_t)p7.x * D_IN))[lane];
        a0 += w0 * bf2f(r0.x) + w1 * bf2f(r1.x) + w2 * bf2f(r2.x) + w3 * bf2f(r3.x);
        a1 += w0 * bf2f(r0.y) + w1 * bf2f(r1.y) + w2 * bf2f(r2.y) + w3 * bf2f(r3.y);
        a2 += w0 * bf2f(r0.z) + w1 * bf2f(r1.z) + w2 * bf2f(r2.z) + w3 * bf2f(r3.z);
        a3 += w0 * bf2f(r0.w) + w1 * bf2f(r1.w) + w2 * bf2f(r2.w) + w3 * bf2f(r3.w);
        c0 += w4 * bf2f(r4.x) + w5 * bf2f(r5.x) + w6 * bf2f(r6.x) + w7 * bf2f(r7.x);
        c1 += w4 * bf2f(r4.y) + w5 * bf2f(r5.y) + w6 * bf2f(r6.y) + w7 * bf2f(r7.y);
        c2 += w4 * bf2f(r4.z) + w5 * bf2f(r5.z) + w6 * bf2f(r6.z) + w7 * bf2f(r7.z);
        c3 += w4 * bf2f(r4.w) + w5 * bf2f(r5.w) + w6 * bf2f(r6.w) + w7 * bf2f(r7.w);
    }
    for (; i + 4 <= end; i += 4) {
        int2 p0 = perm[i + 0], p1 = perm[i + 1], p2 = perm[i + 2], p3 = perm[i + 3];
        float w0 = __int_as_float(p0.y), w1 = __int_as_float(p1.y);
        float w2 = __int_as_float(p2.y), w3 = __int_as_float(p3.y);
        ushort4 r0 = ((const ushort4*)(vb + (size_t)p0.x * D_IN))[lane];
        ushort4 r1 = ((const ushort4*)(vb + (size_t)p1.x * D_IN))[lane];
        ushort4 r2 = ((const ushort4*)(vb + (size_t)p2.x * D_IN))[lane];
        ushort4 r3 = ((const ushort4*)(vb + (size_t)p3.x * D_IN))[lane];
        a0 += w0 * bf2f(r0.x) + w1 * bf2f(r1.x) + w2 * bf2f(r2.x) + w3 * bf2f(r3.x);
        a1 += w0 * bf2f(r0.y) + w1 * bf2f(r1.y) + w2 * bf2f(r2.y) + w3 * bf2f(r3.y);
        a2 += w0 * bf2f(r0.z) + w1 * bf2f(r1.z) + w2 * bf2f(r2.z) + w3 * bf2f(r3.z);
        a3 += w0 * bf2f(r0.w) + w1 * bf2f(r1.w) + w2 * bf2f(r2.w) + w3 * bf2f(r3.w);
    }
    for (; i < end; ++i) {
        int2 p = perm[i];
        float w = __int_as_float(p.y);
        ushort4 r = ((const ushort4*)(vb + (size_t)p.x * D_IN))[lane];
        a0 += w * bf2f(r.x); a1 += w * bf2f(r.y);
        a2 += w * bf2f(r.z); a3 += w * bf2f(r.w);
    }
    a0 += c0; a1 += c1; a2 += c2; a3 += c3;
    float eps = eps_p[0];
    ushort4 m = ((const ushort4*)(vb + (size_t)node * D_IN))[lane];
    a0 += eps * bf2f(m.x); a1 += eps * bf2f(m.y);
    a2 += eps * bf2f(m.z); a3 += eps * bf2f(m.w);
    ((ushort4*)(aggb + (size_t)node * D_IN))[lane] =
        make_ushort4(f2bf(a0), f2bf(a1), f2bf(a2), f2bf(a3));
}

// ---------------------------------------------------------------------------
// Fused MLP, 64-row tile, 256 thr / 4 waves, reg-pipelined K-loops
// (byte-identical to R6's proven 59.4us version; acc lives in AGPRs ->
//  ~256 regs/wave -> 2 blocks/CU is the hard occupancy cap).
// ---------------------------------------------------------------------------
#define HS_IDX(row, col) ((row) * 512 + ((col) ^ (((row) & 7) << 3)))
#define AT_IDX(row, col) ((row) * 256 + ((col) ^ (((row) & 7) << 3)))

__global__ __launch_bounds__(256, 2) void mlp_kernel(
    const ushort* __restrict__ A, const ushort* __restrict__ w1p,
    const ushort* __restrict__ w2p,
    const float* __restrict__ b1, const float* __restrict__ g1, const float* __restrict__ be1,
    const float* __restrict__ b2, const float* __restrict__ g2, const float* __restrict__ be2,
    float* __restrict__ out, int N) {
    __shared__ ushort hs[32768];      // 64 KB
    __shared__ float redf[640];

    int t = threadIdx.x;
    int w = t >> 6, lane = t & 63;
    int row0 = blockIdx.x * 64;
    int fr = lane & 15, q = lane >> 4, kb = q * 8;

    // ---- stage A-tile once: 8 coalesced 1KB loads/wave, source-swizzled ----
    #pragma unroll
    for (int j = 0; j < 8; ++j) {
        int p = (w * 8 + j) * 64 + lane;
        int row = p >> 5, cbs = p & 31;
        int colblk = cbs ^ (row & 7);
        int ar = row0 + row; if (ar > N - 1) ar = N - 1;
        const ushort* gp = A + (size_t)ar * D_IN + colblk * 8;
        __builtin_amdgcn_global_load_lds(
            (const __attribute__((address_space(1))) void*)gp,
            (__attribute__((address_space(3))) void*)(&hs[(w * 8 + j) * 512]),
            16, 0, 0);
    }

    bf16x8 bfb[2][8];
    #pragma unroll
    for (int c = 0; c < 8; ++c)
        bfb[0][c] = *(const bf16x8*)(w1p + (size_t)((w * 8 + c) * 64 + lane) * 8);

    __syncthreads();

    f32x4 acc[4][8];
    #pragma unroll
    for (int m = 0; m < 4; ++m)
        #pragma unroll
        for (int c = 0; c < 8; ++c) {
            f32x4 z = {0.f, 0.f, 0.f, 0.f};
            acc[m][c] = z;
        }

    #pragma unroll
    for (int ks = 0; ks < 8; ++ks) {
        const int cur = ks & 1, nxt = cur ^ 1;
        if (ks < 7) {
            #pragma unroll
            for (int c = 0; c < 8; ++c)
                bfb[nxt][c] = *(const bf16x8*)(w1p +
                    (size_t)(((ks + 1) * 32 + w * 8 + c) * 64 + lane) * 8);
        }
        bf16x8 af[4];
        #pragma unroll
        for (int m = 0; m < 4; ++m)
            af[m] = *(const bf16x8*)&hs[AT_IDX(m * 16 + fr, ks * 32 + kb)];
        #pragma unroll
        for (int m = 0; m < 4; ++m)
            #pragma unroll
            for (int c = 0; c < 8; ++c)
                acc[m][c] = __builtin_amdgcn_mfma_f32_16x16x32_bf16(af[m], bfb[cur][c], acc[m][c], 0, 0, 0);
    }

    {
        float bi[8], gg[8], bb[8];
        #pragma unroll
        for (int c = 0; c < 8; ++c) {
            int col = w * 128 + c * 16 + fr;
            bi[c] = b1[col]; gg[c] = g1[col]; bb[c] = be1[col];
        }
        #pragma unroll
        for (int m = 0; m < 4; ++m) {
            #pragma unroll
            for (int r = 0; r < 4; ++r) {
                float s = 0.f, sq = 0.f;
                #pragma unroll
                for (int c = 0; c < 8; ++c) {
                    float x = acc[m][c][r] + bi[c];
                    acc[m][c][r] = x;
                    s += x; sq += x * x;
                }
                #pragma unroll
                for (int o = 1; o < 16; o <<= 1) {
                    s  += __shfl_xor(s, o, 64);
                    sq += __shfl_xor(sq, o, 64);
                }
                if (fr == 0) {
                    int row = m * 16 + q * 4 + r;
                    redf[row * 4 + w]       = s;
                    redf[256 + row * 4 + w] = sq;
                }
            }
        }
        __syncthreads();
        if (t < 64) {
            float s  = redf[t * 4 + 0] + redf[t * 4 + 1] + redf[t * 4 + 2] + redf[t * 4 + 3];
            float sq = redf[256 + t * 4 + 0] + redf[256 + t * 4 + 1] +
                       redf[256 + t * 4 + 2] + redf[256 + t * 4 + 3];
            float mu = s / (float)D_HID;
            float var = sq / (float)D_HID - mu * mu;
            redf[512 + t] = mu;
            redf[576 + t] = rsqrtf(var + LN_EPS);
        }
        __syncthreads();
        #pragma unroll
        for (int m = 0; m < 4; ++m) {
            #pragma unroll
            for (int r = 0; r < 4; ++r) {
                int row = m * 16 + q * 4 + r;
                float mu = redf[512 + row], rs = redf[576 + row];
                #pragma unroll
                for (int c = 0; c < 8; ++c) {
                    int col = w * 128 + c * 16 + fr;
                    float y = (acc[m][c][r] - mu) * rs * gg[c] + bb[c];
                    hs[HS_IDX(row, col)] = f2bf(fmaxf(y, 0.f));
                }
            }
        }
    }

    bf16x8 bf2b[2][4][2];
    #pragma unroll
    for (int c = 0; c < 4; ++c)
        #pragma unroll
        for (int h = 0; h < 2; ++h)
            bf2b[0][c][h] = *(const bf16x8*)(w2p +
                (size_t)(((0 + h) * 16 + w * 4 + c) * 64 + lane) * 8);

    __syncthreads();

    f32x4 acc2[4][4];
    #pragma unroll
    for (int m = 0; m < 4; ++m)
        #pragma unroll
        for (int c = 0; c < 4; ++c) {
            f32x4 z = {0.f, 0.f, 0.f, 0.f};
            acc2[m][c] = z;
        }

    #pragma unroll
    for (int s2 = 0; s2 < 8; ++s2) {
        const int cur = s2 & 1, nxt = cur ^ 1;
        if (s2 < 7) {
            #pragma unroll
            for (int c = 0; c < 4; ++c)
                #pragma unroll
                for (int h = 0; h < 2; ++h)
                    bf2b[nxt][c][h] = *(const bf16x8*)(w2p +
                        (size_t)(((2 * (s2 + 1) + h) * 16 + w * 4 + c) * 64 + lane) * 8);
        }
        bf16x8 af2[4][2];
        #pragma unroll
        for (int m = 0; m < 4; ++m)
            #pragma unroll
            for (int h = 0; h < 2; ++h)
                af2[m][h] = *(const bf16x8*)&hs[HS_IDX(m * 16 + fr, s2 * 64 + h * 32 + kb)];
        #pragma unroll
        for (int m = 0; m < 4; ++m)
            #pragma unroll
            for (int c = 0; c < 4; ++c)
                #pragma unroll
                for (int h = 0; h < 2; ++h)
                    acc2[m][c] = __builtin_amdgcn_mfma_f32_16x16x32_bf16(af2[m][h], bf2b[cur][c][h], acc2[m][c], 0, 0, 0);
    }

    {
        float bi[4], gg[4], bb[4];
        #pragma unroll
        for (int c = 0; c < 4; ++c) {
            int col = w * 64 + c * 16 + fr;
            bi[c] = b2[col]; gg[c] = g2[col]; bb[c] = be2[col];
        }
        #pragma unroll
        for (int m = 0; m < 4; ++m) {
            #pragma unroll
            for (int r = 0; r < 4; ++r) {
                float s = 0.f, sq = 0.f;
                #pragma unroll
                for (int c = 0; c < 4; ++c) {
                    float x = acc2[m][c][r] + bi[c];
                    acc2[m][c][r] = x;
                    s += x; sq += x * x;
                }
                #pragma unroll
                for (int o = 1; o < 16; o <<= 1) {
                    s  += __shfl_xor(s, o, 64);
                    sq += __shfl_xor(sq, o, 64);
                }
                if (fr == 0) {
                    int row = m * 16 + q * 4 + r;
                    redf[row * 4 + w]       = s;
                    redf[256 + row * 4 + w] = sq;
                }
            }
        }
        __syncthreads();
        if (t < 64) {
            float s  = redf[t * 4 + 0] + redf[t * 4 + 1] + redf[t * 4 + 2] + redf[t * 4 + 3];
            float sq = redf[256 + t * 4 + 0] + redf[256 + t * 4 + 1] +
                       redf[256 + t * 4 + 2] + redf[256 + t * 4 + 3];
            float mu = s / (float)D_OUT;
            float var = sq / (float)D_OUT - mu * mu;
            redf[512 + t] = mu;
            redf[576 + t] = rsqrtf(var + LN_EPS);
        }
        __syncthreads();
        #pragma unroll
        for (int m = 0; m < 4; ++m) {
            #pragma unroll
            for (int r = 0; r < 4; ++r) {
                int row = m * 16 + q * 4 + r;
                int grow = row0 + row;
                if (grow >= N) continue;
                float mu = redf[512 + row], rs = redf[576 + row];
                #pragma unroll
                for (int c = 0; c < 4; ++c) {
                    int col = w * 64 + c * 16 + fr;
                    float y = (acc2[m][c][r] - mu) * rs * gg[c] + bb[c];
                    out[(size_t)grow * D_OUT + col] = fmaxf(y, 0.f);
                }
            }
        }
    }
}

// ---------------------------------------------------------------------------
extern "C" void kernel_launch(void* const* d_in, const int* in_sizes, int n_in,
                              void* d_out, int out_size, void* d_ws, size_t ws_size,
                              hipStream_t stream) {
    const float* v     = (const float*)d_in[0];
    const float* ew    = (const float*)d_in[1];
    const float* eps   = (const float*)d_in[2];
    const float* w1    = (const float*)d_in[3];
    const float* b1    = (const float*)d_in[4];
    const float* g1    = (const float*)d_in[5];
    const float* beta1 = (const float*)d_in[6];
    const float* w2    = (const float*)d_in[7];
    const float* b2    = (const float*)d_in[8];
    const float* g2    = (const float*)d_in[9];
    const float* beta2 = (const float*)d_in[10];
    const int*   src   = (const int*)d_in[11];
    const int*   dst   = (const int*)d_in[12];

    int N = in_sizes[0] / D_IN;     // 50000
    int E = in_sizes[1];            // 800000

    float* out = (float*)d_out;

    // workspace layout (256B-aligned chunks)
    char* ws = (char*)d_ws;
    size_t off = 0;
    ushort* vb   = (ushort*)(ws + off); off += (size_t)N * D_IN * 2;            // 25.6 MB
    ushort* aggb = (ushort*)(ws + off); off += (size_t)N * D_IN * 2;            // 25.6 MB
    ushort* w1p  = (ushort*)(ws + off); off += (size_t)D_HID * D_IN * 2;        // 256 KB
    ushort* w2p  = (ushort*)(ws + off); off += (size_t)D_OUT * D_HID * 2;       // 256 KB
    int* offs     = (int*)(ws + off); off += (size_t)(N + 256) * 4;
    int* cnt      = (int*)(ws + off); off += (size_t)(N + 256) * 4;             // zeroed
    int* done     = (int*)(ws + off); off += 256;                               // zeroed (contig w/ cnt)
    int* bsum     = (int*)(ws + off); off += 2048;
    int* bases    = (int*)(ws + off); off += 2048;
    int* rank     = (int*)(ws + off); off += (size_t)E * 4;                     // 3.2 MB
    int2* perm    = (int2*)(ws + off); off += (size_t)E * 8;                    // 6.4 MB

    int n4v = N * (D_IN / 4);
    int bv = (n4v + 255) / 256;
    int bw = 256;                     // 65536 float4s of weights
    int be = (E + 255) / 256;
    int nb = (N + SCAN_B) / SCAN_B;   // covers index N (chunk-local totals)

    // 0) zero histogram + done counter (contiguous)
    hipMemsetAsync(cnt, 0, (size_t)(N + 256) * 4 + 256, stream);

    // 1) prep: casts + packed weights + edge hist/rank
    prep_kernel<<<bv + bw + be, 256, 0, stream>>>(v, w1, w2, vb, w1p, w2p,
                                                  dst, rank, cnt, n4v, E, bv, bw);

    // 2) merged CSR scan (single launch, last-block finisher)
    scan_kernel<<<nb, SCAN_B, 0, stream>>>(cnt, offs, bsum, bases, done, N, nb);

    // 3) counting-sort fill (no atomics)
    fill_kernel<<<be, 256, 0, stream>>>(src, dst, ew, rank, offs, bases, perm, E);

    // 4) aggregate (bf16 gather), high-TLP standalone
    aggregate_kernel<<<(N + 3) / 4, 256, 0, stream>>>(vb, eps, offs, bases, perm, aggb, N);

    // 5) fused MLP (R6-proven 64-row / 256-thread)
    int mblocks = (N + 63) / 64;
    mlp_kernel<<<mblocks, 256, 0, stream>>>(aggb, w1p, w2p,
                                            b1, g1, beta1, b2, g2, beta2, out, N);
}

// Round 12
// 297.192 us; speedup vs baseline: 1.0404x; 1.0404x over previous
//
#include <hip/hip_runtime.h>

#define D_IN 256
#define D_HID 512
#define D_OUT 256
#define LN_EPS 1e-5f
#define SCAN_B 512

typedef __attribute__((ext_vector_type(8))) short bf16x8;
typedef __attribute__((ext_vector_type(4))) float f32x4;

__device__ __forceinline__ ushort f2bf(float x) {
    union { float f; unsigned u; } c; c.f = x;
    unsigned r = c.u + 0x7FFFu + ((c.u >> 16) & 1u);   // round-to-nearest-even
    return (ushort)(r >> 16);
}
__device__ __forceinline__ float bf2f(unsigned b) {
    union { unsigned u; float f; } c; c.u = b << 16;
    return c.f;
}

// ---------------------------------------------------------------------------
// prep: cvt v->bf16 | cvt w1,w2->bf16 PACKED in MFMA-fragment order |
//       edge hist+rank (cnt pre-zeroed by hipMemsetAsync)
// ---------------------------------------------------------------------------
__global__ void prep_kernel(const float* __restrict__ v, const float* __restrict__ w1,
                            const float* __restrict__ w2, ushort* __restrict__ vb,
                            ushort* __restrict__ w1p, ushort* __restrict__ w2p,
                            const int* __restrict__ dst, int* __restrict__ rank,
                            int* __restrict__ cnt, int n4v, int E,
                            int bv, int bw) {
    int b = blockIdx.x, t = threadIdx.x;
    if (b < bv) {
        int i = b * 256 + t;
        if (i < n4v) {
            float4 x = ((const float4*)v)[i];
            ((ushort4*)vb)[i] = make_ushort4(f2bf(x.x), f2bf(x.y), f2bf(x.z), f2bf(x.w));
        }
    } else if (b < bv + bw) {
        int j = (b - bv) * 256 + t;     // 0..65535 float4s (w1: first 32768)
        if (j < 32768) {                // w1: [512][256] fp32
            int f = j * 4;
            int row = f >> 8, col = f & 255;
            float4 x = ((const float4*)w1)[j];
            int rb = row >> 4, fr = row & 15;
            int kb32 = col >> 5, q = (col & 31) >> 3, e = col & 7;
            int chunk = (kb32 * 32 + rb) * 64 + q * 16 + fr;
            *(ushort4*)(w1p + chunk * 8 + e) =
                make_ushort4(f2bf(x.x), f2bf(x.y), f2bf(x.z), f2bf(x.w));
        } else {                        // w2: [256][512] fp32
            int k = j - 32768;
            int f = k * 4;
            int row = f >> 9, col = f & 511;
            float4 x = ((const float4*)w2)[k];
            int rb = row >> 4, fr = row & 15;
            int kb32 = col >> 5, q = (col & 31) >> 3, e = col & 7;
            int chunk = (kb32 * 16 + rb) * 64 + q * 16 + fr;
            *(ushort4*)(w2p + chunk * 8 + e) =
                make_ushort4(f2bf(x.x), f2bf(x.y), f2bf(x.z), f2bf(x.w));
        }
    } else {
        int e = (b - bv - bw) * 256 + t;
        if (e < E) rank[e] = atomicAdd(&cnt[dst[e]], 1);
    }
}

// ---------------------------------------------------------------------------
// CSR offsets: two-level scan over cnt (R6-proven)
// ---------------------------------------------------------------------------
__global__ __launch_bounds__(SCAN_B) void scan1_kernel(const int* __restrict__ cnt,
                                                       int* __restrict__ offs,
                                                       int* __restrict__ bsum, int n) {
    __shared__ int s[SCAN_B];
    int i = blockIdx.x * SCAN_B + threadIdx.x;
    int x = (i < n) ? cnt[i] : 0;
    s[threadIdx.x] = x;
    __syncthreads();
    for (int o = 1; o < SCAN_B; o <<= 1) {
        int t = (threadIdx.x >= (unsigned)o) ? s[threadIdx.x - o] : 0;
        __syncthreads();
        s[threadIdx.x] += t;
        __syncthreads();
    }
    if (i < n) offs[i] = s[threadIdx.x] - x;
    if (threadIdx.x == SCAN_B - 1) bsum[blockIdx.x] = s[threadIdx.x];
}

__global__ __launch_bounds__(SCAN_B) void scan3_kernel(int* __restrict__ offs,
                                                       const int* __restrict__ bsum,
                                                       int n, int E, int nb) {
    __shared__ int s[SCAN_B];
    int t = threadIdx.x;
    s[t] = (t < nb && t < (int)blockIdx.x) ? bsum[t] : 0;
    __syncthreads();
    for (int o = SCAN_B / 2; o > 0; o >>= 1) {
        if (t < o) s[t] += s[t + o];
        __syncthreads();
    }
    int base = s[0];
    int i = blockIdx.x * SCAN_B + t;
    if (i < n) offs[i] += base;
    if (i == 0) offs[n] = E;
}

// counting-sort fill, NO atomics: slot = offs[dst] + rank (unique by constr.)
__global__ void fill_kernel(const int* __restrict__ src, const int* __restrict__ dst,
                            const float* __restrict__ ew, const int* __restrict__ rank,
                            const int* __restrict__ offs,
                            int2* __restrict__ perm, int E) {
    int e = blockIdx.x * 256 + threadIdx.x;
    if (e >= E) return;
    int p = offs[dst[e]] + rank[e];
    perm[p] = make_int2(src[e], __float_as_int(ew[e]));
}

// ---------------------------------------------------------------------------
// agg_bf16[n] = bf16( eps*vb[n] + sum_{e:dst=n} w_e * vb[src_e] )
// one wave/node, 12.5k blocks for TLP (proven: 59.6us, 3.6TB/s, occ 60%)
// ---------------------------------------------------------------------------
__global__ __launch_bounds__(256) void aggregate_kernel(
    const ushort* __restrict__ vb, const float* __restrict__ eps_p,
    const int* __restrict__ offs, const int2* __restrict__ perm,
    ushort* __restrict__ aggb, int N) {
    int node = blockIdx.x * 4 + (threadIdx.x >> 6);
    if (node >= N) return;
    int lane = threadIdx.x & 63;
    int beg = offs[node], end = offs[node + 1];
    float a0 = 0.f, a1 = 0.f, a2 = 0.f, a3 = 0.f;
    float c0 = 0.f, c1 = 0.f, c2 = 0.f, c3 = 0.f;

    int i = beg;
    for (; i + 8 <= end; i += 8) {
        int2 p0 = perm[i + 0], p1 = perm[i + 1], p2 = perm[i + 2], p3 = perm[i + 3];
        int2 p4 = perm[i + 4], p5 = perm[i + 5], p6 = perm[i + 6], p7 = perm[i + 7];
        float w0 = __int_as_float(p0.y), w1 = __int_as_float(p1.y);
        float w2 = __int_as_float(p2.y), w3 = __int_as_float(p3.y);
        float w4 = __int_as_float(p4.y), w5 = __int_as_float(p5.y);
        float w6 = __int_as_float(p6.y), w7 = __int_as_float(p7.y);
        ushort4 r0 = ((const ushort4*)(vb + (size_t)p0.x * D_IN))[lane];
        ushort4 r1 = ((const ushort4*)(vb + (size_t)p1.x * D_IN))[lane];
        ushort4 r2 = ((const ushort4*)(vb + (size_t)p2.x * D_IN))[lane];
        ushort4 r3 = ((const ushort4*)(vb + (size_t)p3.x * D_IN))[lane];
        ushort4 r4 = ((const ushort4*)(vb + (size_t)p4.x * D_IN))[lane];
        ushort4 r5 = ((const ushort4*)(vb + (size_t)p5.x * D_IN))[lane];
        ushort4 r6 = ((const ushort4*)(vb + (size_t)p6.x * D_IN))[lane];
        ushort4 r7 = ((const ushort4*)(vb + (size_t)p7.x * D_IN))[lane];
        a0 += w0 * bf2f(r0.x) + w1 * bf2f(r1.x) + w2 * bf2f(r2.x) + w3 * bf2f(r3.x);
        a1 += w0 * bf2f(r0.y) + w1 * bf2f(r1.y) + w2 * bf2f(r2.y) + w3 * bf2f(r3.y);
        a2 += w0 * bf2f(r0.z) + w1 * bf2f(r1.z) + w2 * bf2f(r2.z) + w3 * bf2f(r3.z);
        a3 += w0 * bf2f(r0.w) + w1 * bf2f(r1.w) + w2 * bf2f(r2.w) + w3 * bf2f(r3.w);
        c0 += w4 * bf2f(r4.x) + w5 * bf2f(r5.x) + w6 * bf2f(r6.x) + w7 * bf2f(r7.x);
        c1 += w4 * bf2f(r4.y) + w5 * bf2f(r5.y) + w6 * bf2f(r6.y) + w7 * bf2f(r7.y);
        c2 += w4 * bf2f(r4.z) + w5 * bf2f(r5.z) + w6 * bf2f(r6.z) + w7 * bf2f(r7.z);
        c3 += w4 * bf2f(r4.w) + w5 * bf2f(r5.w) + w6 * bf2f(r6.w) + w7 * bf2f(r7.w);
    }
    for (; i + 4 <= end; i += 4) {
        int2 p0 = perm[i + 0], p1 = perm[i + 1], p2 = perm[i + 2], p3 = perm[i + 3];
        float w0 = __int_as_float(p0.y), w1 = __int_as_float(p1.y);
        float w2 = __int_as_float(p2.y), w3 = __int_as_float(p3.y);
        ushort4 r0 = ((const ushort4*)(vb + (size_t)p0.x * D_IN))[lane];
        ushort4 r1 = ((const ushort4*)(vb + (size_t)p1.x * D_IN))[lane];
        ushort4 r2 = ((const ushort4*)(vb + (size_t)p2.x * D_IN))[lane];
        ushort4 r3 = ((const ushort4*)(vb + (size_t)p3.x * D_IN))[lane];
        a0 += w0 * bf2f(r0.x) + w1 * bf2f(r1.x) + w2 * bf2f(r2.x) + w3 * bf2f(r3.x);
        a1 += w0 * bf2f(r0.y) + w1 * bf2f(r1.y) + w2 * bf2f(r2.y) + w3 * bf2f(r3.y);
        a2 += w0 * bf2f(r0.z) + w1 * bf2f(r1.z) + w2 * bf2f(r2.z) + w3 * bf2f(r3.z);
        a3 += w0 * bf2f(r0.w) + w1 * bf2f(r1.w) + w2 * bf2f(r2.w) + w3 * bf2f(r3.w);
    }
    for (; i < end; ++i) {
        int2 p = perm[i];
        float w = __int_as_float(p.y);
        ushort4 r = ((const ushort4*)(vb + (size_t)p.x * D_IN))[lane];
        a0 += w * bf2f(r.x); a1 += w * bf2f(r.y);
        a2 += w * bf2f(r.z); a3 += w * bf2f(r.w);
    }
    a0 += c0; a1 += c1; a2 += c2; a3 += c3;
    float eps = eps_p[0];
    ushort4 m = ((const ushort4*)(vb + (size_t)node * D_IN))[lane];
    a0 += eps * bf2f(m.x); a1 += eps * bf2f(m.y);
    a2 += eps * bf2f(m.z); a3 += eps * bf2f(m.w);
    ((ushort4*)(aggb + (size_t)node * D_IN))[lane] =
        make_ushort4(f2bf(a0), f2bf(a1), f2bf(a2), f2bf(a3));
}

// ---------------------------------------------------------------------------
// Fused MLP, 64-row tile, 256 thr / 4 waves, reg-pipelined K-loops
// (R6-proven 59.4us; acc in AGPRs -> ~256 regs/wave -> 2 blocks/CU cap)
// ---------------------------------------------------------------------------
#define HS_IDX(row, col) ((row) * 512 + ((col) ^ (((row) & 7) << 3)))
#define AT_IDX(row, col) ((row) * 256 + ((col) ^ (((row) & 7) << 3)))

__global__ __launch_bounds__(256, 2) void mlp_kernel(
    const ushort* __restrict__ A, const ushort* __restrict__ w1p,
    const ushort* __restrict__ w2p,
    const float* __restrict__ b1, const float* __restrict__ g1, const float* __restrict__ be1,
    const float* __restrict__ b2, const float* __restrict__ g2, const float* __restrict__ be2,
    float* __restrict__ out, int N) {
    __shared__ ushort hs[32768];      // 64 KB
    __shared__ float redf[640];

    int t = threadIdx.x;
    int w = t >> 6, lane = t & 63;
    int row0 = blockIdx.x * 64;
    int fr = lane & 15, q = lane >> 4, kb = q * 8;

    // ---- stage A-tile once: 8 coalesced 1KB loads/wave, source-swizzled ----
    #pragma unroll
    for (int j = 0; j < 8; ++j) {
        int p = (w * 8 + j) * 64 + lane;
        int row = p >> 5, cbs = p & 31;
        int colblk = cbs ^ (row & 7);
        int ar = row0 + row; if (ar > N - 1) ar = N - 1;
        const ushort* gp = A + (size_t)ar * D_IN + colblk * 8;
        __builtin_amdgcn_global_load_lds(
            (const __attribute__((address_space(1))) void*)gp,
            (__attribute__((address_space(3))) void*)(&hs[(w * 8 + j) * 512]),
            16, 0, 0);
    }

    bf16x8 bfb[2][8];
    #pragma unroll
    for (int c = 0; c < 8; ++c)
        bfb[0][c] = *(const bf16x8*)(w1p + (size_t)((w * 8 + c) * 64 + lane) * 8);

    __syncthreads();

    f32x4 acc[4][8];
    #pragma unroll
    for (int m = 0; m < 4; ++m)
        #pragma unroll
        for (int c = 0; c < 8; ++c) {
            f32x4 z = {0.f, 0.f, 0.f, 0.f};
            acc[m][c] = z;
        }

    #pragma unroll
    for (int ks = 0; ks < 8; ++ks) {
        const int cur = ks & 1, nxt = cur ^ 1;
        if (ks < 7) {
            #pragma unroll
            for (int c = 0; c < 8; ++c)
                bfb[nxt][c] = *(const bf16x8*)(w1p +
                    (size_t)(((ks + 1) * 32 + w * 8 + c) * 64 + lane) * 8);
        }
        bf16x8 af[4];
        #pragma unroll
        for (int m = 0; m < 4; ++m)
            af[m] = *(const bf16x8*)&hs[AT_IDX(m * 16 + fr, ks * 32 + kb)];
        #pragma unroll
        for (int m = 0; m < 4; ++m)
            #pragma unroll
            for (int c = 0; c < 8; ++c)
                acc[m][c] = __builtin_amdgcn_mfma_f32_16x16x32_bf16(af[m], bfb[cur][c], acc[m][c], 0, 0, 0);
    }

    {
        float bi[8], gg[8], bb[8];
        #pragma unroll
        for (int c = 0; c < 8; ++c) {
            int col = w * 128 + c * 16 + fr;
            bi[c] = b1[col]; gg[c] = g1[col]; bb[c] = be1[col];
        }
        #pragma unroll
        for (int m = 0; m < 4; ++m) {
            #pragma unroll
            for (int r = 0; r < 4; ++r) {
                float s = 0.f, sq = 0.f;
                #pragma unroll
                for (int c = 0; c < 8; ++c) {
                    float x = acc[m][c][r] + bi[c];
                    acc[m][c][r] = x;
                    s += x; sq += x * x;
                }
                #pragma unroll
                for (int o = 1; o < 16; o <<= 1) {
                    s  += __shfl_xor(s, o, 64);
                    sq += __shfl_xor(sq, o, 64);
                }
                if (fr == 0) {
                    int row = m * 16 + q * 4 + r;
                    redf[row * 4 + w]       = s;
                    redf[256 + row * 4 + w] = sq;
                }
            }
        }
        __syncthreads();
        if (t < 64) {
            float s  = redf[t * 4 + 0] + redf[t * 4 + 1] + redf[t * 4 + 2] + redf[t * 4 + 3];
            float sq = redf[256 + t * 4 + 0] + redf[256 + t * 4 + 1] +
                       redf[256 + t * 4 + 2] + redf[256 + t * 4 + 3];
            float mu = s / (float)D_HID;
            float var = sq / (float)D_HID - mu * mu;
            redf[512 + t] = mu;
            redf[576 + t] = rsqrtf(var + LN_EPS);
        }
        __syncthreads();
        #pragma unroll
        for (int m = 0; m < 4; ++m) {
            #pragma unroll
            for (int r = 0; r < 4; ++r) {
                int row = m * 16 + q * 4 + r;
                float mu = redf[512 + row], rs = redf[576 + row];
                #pragma unroll
                for (int c = 0; c < 8; ++c) {
                    int col = w * 128 + c * 16 + fr;
                    float y = (acc[m][c][r] - mu) * rs * gg[c] + bb[c];
                    hs[HS_IDX(row, col)] = f2bf(fmaxf(y, 0.f));
                }
            }
        }
    }

    bf16x8 bf2b[2][4][2];
    #pragma unroll
    for (int c = 0; c < 4; ++c)
        #pragma unroll
        for (int h = 0; h < 2; ++h)
            bf2b[0][c][h] = *(const bf16x8*)(w2p +
                (size_t)(((0 + h) * 16 + w * 4 + c) * 64 + lane) * 8);

    __syncthreads();

    f32x4 acc2[4][4];
    #pragma unroll
    for (int m = 0; m < 4; ++m)
        #pragma unroll
        for (int c = 0; c < 4; ++c) {
            f32x4 z = {0.f, 0.f, 0.f, 0.f};
            acc2[m][c] = z;
        }

    #pragma unroll
    for (int s2 = 0; s2 < 8; ++s2) {
        const int cur = s2 & 1, nxt = cur ^ 1;
        if (s2 < 7) {
            #pragma unroll
            for (int c = 0; c < 4; ++c)
                #pragma unroll
                for (int h = 0; h < 2; ++h)
                    bf2b[nxt][c][h] = *(const bf16x8*)(w2p +
                        (size_t)(((2 * (s2 + 1) + h) * 16 + w * 4 + c) * 64 + lane) * 8);
        }
        bf16x8 af2[4][2];
        #pragma unroll
        for (int m = 0; m < 4; ++m)
            #pragma unroll
            for (int h = 0; h < 2; ++h)
                af2[m][h] = *(const bf16x8*)&hs[HS_IDX(m * 16 + fr, s2 * 64 + h * 32 + kb)];
        #pragma unroll
        for (int m = 0; m < 4; ++m)
            #pragma unroll
            for (int c = 0; c < 4; ++c)
                #pragma unroll
                for (int h = 0; h < 2; ++h)
                    acc2[m][c] = __builtin_amdgcn_mfma_f32_16x16x32_bf16(af2[m][h], bf2b[cur][c][h], acc2[m][c], 0, 0, 0);
    }

    {
        float bi[4], gg[4], bb[4];
        #pragma unroll
        for (int c = 0; c < 4; ++c) {
            int col = w * 64 + c * 16 + fr;
            bi[c] = b2[col]; gg[c] = g2[col]; bb[c] = be2[col];
        }
        #pragma unroll
        for (int m = 0; m < 4; ++m) {
            #pragma unroll
            for (int r = 0; r < 4; ++r) {
                float s = 0.f, sq = 0.f;
                #pragma unroll
                for (int c = 0; c < 4; ++c) {
                    float x = acc2[m][c][r] + bi[c];
                    acc2[m][c][r] = x;
                    s += x; sq += x * x;
                }
                #pragma unroll
                for (int o = 1; o < 16; o <<= 1) {
                    s  += __shfl_xor(s, o, 64);
                    sq += __shfl_xor(sq, o, 64);
                }
                if (fr == 0) {
                    int row = m * 16 + q * 4 + r;
                    redf[row * 4 + w]       = s;
                    redf[256 + row * 4 + w] = sq;
                }
            }
        }
        __syncthreads();
        if (t < 64) {
            float s  = redf[t * 4 + 0] + redf[t * 4 + 1] + redf[t * 4 + 2] + redf[t * 4 + 3];
            float sq = redf[256 + t * 4 + 0] + redf[256 + t * 4 + 1] +
                       redf[256 + t * 4 + 2] + redf[256 + t * 4 + 3];
            float mu = s / (float)D_OUT;
            float var = sq / (float)D_OUT - mu * mu;
            redf[512 + t] = mu;
            redf[576 + t] = rsqrtf(var + LN_EPS);
        }
        __syncthreads();
        #pragma unroll
        for (int m = 0; m < 4; ++m) {
            #pragma unroll
            for (int r = 0; r < 4; ++r) {
                int row = m * 16 + q * 4 + r;
                int grow = row0 + row;
                if (grow >= N) continue;
                float mu = redf[512 + row], rs = redf[576 + row];
                #pragma unroll
                for (int c = 0; c < 4; ++c) {
                    int col = w * 64 + c * 16 + fr;
                    float y = (acc2[m][c][r] - mu) * rs * gg[c] + bb[c];
                    out[(size_t)grow * D_OUT + col] = fmaxf(y, 0.f);
                }
            }
        }
    }
}

// ---------------------------------------------------------------------------
extern "C" void kernel_launch(void* const* d_in, const int* in_sizes, int n_in,
                              void* d_out, int out_size, void* d_ws, size_t ws_size,
                              hipStream_t stream) {
    const float* v     = (const float*)d_in[0];
    const float* ew    = (const float*)d_in[1];
    const float* eps   = (const float*)d_in[2];
    const float* w1    = (const float*)d_in[3];
    const float* b1    = (const float*)d_in[4];
    const float* g1    = (const float*)d_in[5];
    const float* beta1 = (const float*)d_in[6];
    const float* w2    = (const float*)d_in[7];
    const float* b2    = (const float*)d_in[8];
    const float* g2    = (const float*)d_in[9];
    const float* beta2 = (const float*)d_in[10];
    const int*   src   = (const int*)d_in[11];
    const int*   dst   = (const int*)d_in[12];

    int N = in_sizes[0] / D_IN;     // 50000
    int E = in_sizes[1];            // 800000

    float* out = (float*)d_out;

    // workspace layout (256B-aligned chunks)
    char* ws = (char*)d_ws;
    size_t off = 0;
    ushort* vb   = (ushort*)(ws + off); off += (size_t)N * D_IN * 2;            // 25.6 MB
    ushort* aggb = (ushort*)(ws + off); off += (size_t)N * D_IN * 2;            // 25.6 MB
    ushort* w1p  = (ushort*)(ws + off); off += (size_t)D_HID * D_IN * 2;        // 256 KB
    ushort* w2p  = (ushort*)(ws + off); off += (size_t)D_OUT * D_HID * 2;       // 256 KB
    int* offs     = (int*)(ws + off); off += (size_t)(N + 256) * 4;
    int* cnt      = (int*)(ws + off); off += (size_t)(N + 256) * 4;             // zeroed
    int* bsum     = (int*)(ws + off); off += 1024;
    int* rank     = (int*)(ws + off); off += (size_t)E * 4;                     // 3.2 MB
    int2* perm    = (int2*)(ws + off); off += (size_t)E * 8;                    // 6.4 MB

    int n4v = N * (D_IN / 4);
    int bv = (n4v + 255) / 256;
    int bw = 256;                     // 65536 float4s of weights
    int be = (E + 255) / 256;
    int nb = (N + SCAN_B - 1) / SCAN_B;

    // 0) zero the histogram
    hipMemsetAsync(cnt, 0, (size_t)N * 4, stream);

    // 1) prep: casts + packed weights + edge hist/rank
    prep_kernel<<<bv + bw + be, 256, 0, stream>>>(v, w1, w2, vb, w1p, w2p,
                                                  dst, rank, cnt, n4v, E, bv, bw);

    // 2) CSR offsets (two-level scan, proven)
    scan1_kernel<<<nb, SCAN_B, 0, stream>>>(cnt, offs, bsum, N);
    scan3_kernel<<<nb, SCAN_B, 0, stream>>>(offs, bsum, N, E, nb);

    // 3) counting-sort fill (no atomics)
    fill_kernel<<<be, 256, 0, stream>>>(src, dst, ew, rank, offs, perm, E);

    // 4) aggregate (bf16 gather), high-TLP standalone
    aggregate_kernel<<<(N + 3) / 4, 256, 0, stream>>>(vb, eps, offs, perm, aggb, N);

    // 5) fused MLP (R6-proven 64-row / 256-thread)
    int mblocks = (N + 63) / 64;
    mlp_kernel<<<mblocks, 256, 0, stream>>>(aggb, w1p, w2p,
                                            b1, g1, beta1, b2, g2, beta2, out, N);
}

// Round 13
// 291.215 us; speedup vs baseline: 1.0618x; 1.0205x over previous
//
#include <hip/hip_runtime.h>

#define D_IN 256
#define D_HID 512
#define D_OUT 256
#define LN_EPS 1e-5f
#define SCAN_B 512
#define CPAD 16    // cnt stride in ints: one counter per 64B cacheline

typedef __attribute__((ext_vector_type(8))) short bf16x8;
typedef __attribute__((ext_vector_type(4))) float f32x4;

__device__ __forceinline__ ushort f2bf(float x) {
    union { float f; unsigned u; } c; c.f = x;
    unsigned r = c.u + 0x7FFFu + ((c.u >> 16) & 1u);   // round-to-nearest-even
    return (ushort)(r >> 16);
}
__device__ __forceinline__ float bf2f(unsigned b) {
    union { unsigned u; float f; } c; c.u = b << 16;
    return c.f;
}

// ---------------------------------------------------------------------------
// prep: edge hist+rank FIRST (latency tail overlaps streaming blocks) |
//       cvt v->bf16 | cvt w1,w2->bf16 PACKED in MFMA-fragment order
// cnt is padded: one counter per 64B line -> line contention 256 -> 16.
// ---------------------------------------------------------------------------
__global__ void prep_kernel(const float* __restrict__ v, const float* __restrict__ w1,
                            const float* __restrict__ w2, ushort* __restrict__ vb,
                            ushort* __restrict__ w1p, ushort* __restrict__ w2p,
                            const int* __restrict__ dst, int* __restrict__ rank,
                            int* __restrict__ cnt, int n4v, int E,
                            int be, int bv) {
    int b = blockIdx.x, t = threadIdx.x;
    if (b < be) {                       // hist/rank first: overlap atomic latency
        int e = b * 256 + t;
        if (e < E) rank[e] = atomicAdd(&cnt[(size_t)dst[e] * CPAD], 1);
    } else if (b < be + bv) {
        int i = (b - be) * 256 + t;
        if (i < n4v) {
            float4 x = ((const float4*)v)[i];
            ((ushort4*)vb)[i] = make_ushort4(f2bf(x.x), f2bf(x.y), f2bf(x.z), f2bf(x.w));
        }
    } else {
        int j = (b - be - bv) * 256 + t;  // 0..65535 float4s (w1: first 32768)
        if (j < 32768) {                // w1: [512][256] fp32
            int f = j * 4;
            int row = f >> 8, col = f & 255;
            float4 x = ((const float4*)w1)[j];
            int rb = row >> 4, fr = row & 15;
            int kb32 = col >> 5, q = (col & 31) >> 3, e = col & 7;
            int chunk = (kb32 * 32 + rb) * 64 + q * 16 + fr;
            *(ushort4*)(w1p + chunk * 8 + e) =
                make_ushort4(f2bf(x.x), f2bf(x.y), f2bf(x.z), f2bf(x.w));
        } else {                        // w2: [256][512] fp32
            int k = j - 32768;
            int f = k * 4;
            int row = f >> 9, col = f & 511;
            float4 x = ((const float4*)w2)[k];
            int rb = row >> 4, fr = row & 15;
            int kb32 = col >> 5, q = (col & 31) >> 3, e = col & 7;
            int chunk = (kb32 * 16 + rb) * 64 + q * 16 + fr;
            *(ushort4*)(w2p + chunk * 8 + e) =
                make_ushort4(f2bf(x.x), f2bf(x.y), f2bf(x.z), f2bf(x.w));
        }
    }
}

// ---------------------------------------------------------------------------
// CSR offsets: two-level scan over padded cnt (R6-proven structure)
// ---------------------------------------------------------------------------
__global__ __launch_bounds__(SCAN_B) void scan1_kernel(const int* __restrict__ cnt,
                                                       int* __restrict__ offs,
                                                       int* __restrict__ bsum, int n) {
    __shared__ int s[SCAN_B];
    int i = blockIdx.x * SCAN_B + threadIdx.x;
    int x = (i < n) ? cnt[(size_t)i * CPAD] : 0;
    s[threadIdx.x] = x;
    __syncthreads();
    for (int o = 1; o < SCAN_B; o <<= 1) {
        int t = (threadIdx.x >= (unsigned)o) ? s[threadIdx.x - o] : 0;
        __syncthreads();
        s[threadIdx.x] += t;
        __syncthreads();
    }
    if (i < n) offs[i] = s[threadIdx.x] - x;
    if (threadIdx.x == SCAN_B - 1) bsum[blockIdx.x] = s[threadIdx.x];
}

__global__ __launch_bounds__(SCAN_B) void scan3_kernel(int* __restrict__ offs,
                                                       const int* __restrict__ bsum,
                                                       int n, int E, int nb) {
    __shared__ int s[SCAN_B];
    int t = threadIdx.x;
    s[t] = (t < nb && t < (int)blockIdx.x) ? bsum[t] : 0;
    __syncthreads();
    for (int o = SCAN_B / 2; o > 0; o >>= 1) {
        if (t < o) s[t] += s[t + o];
        __syncthreads();
    }
    int base = s[0];
    int i = blockIdx.x * SCAN_B + t;
    if (i < n) offs[i] += base;
    if (i == 0) offs[n] = E;
}

// counting-sort fill, NO atomics: slot = offs[dst] + rank (unique by constr.)
__global__ void fill_kernel(const int* __restrict__ src, const int* __restrict__ dst,
                            const float* __restrict__ ew, const int* __restrict__ rank,
                            const int* __restrict__ offs,
                            int2* __restrict__ perm, int E) {
    int e = blockIdx.x * 256 + threadIdx.x;
    if (e >= E) return;
    int p = offs[dst[e]] + rank[e];
    perm[p] = make_int2(src[e], __float_as_int(ew[e]));
}

// ---------------------------------------------------------------------------
// agg_bf16[n] = bf16( eps*vb[n] + sum_{e:dst=n} w_e * vb[src_e] )
// one wave/node, 12.5k blocks for TLP (proven: 59.6us, 3.6TB/s, occ 60%)
// ---------------------------------------------------------------------------
__global__ __launch_bounds__(256) void aggregate_kernel(
    const ushort* __restrict__ vb, const float* __restrict__ eps_p,
    const int* __restrict__ offs, const int2* __restrict__ perm,
    ushort* __restrict__ aggb, int N) {
    int node = blockIdx.x * 4 + (threadIdx.x >> 6);
    if (node >= N) return;
    int lane = threadIdx.x & 63;
    int beg = offs[node], end = offs[node + 1];
    float a0 = 0.f, a1 = 0.f, a2 = 0.f, a3 = 0.f;
    float c0 = 0.f, c1 = 0.f, c2 = 0.f, c3 = 0.f;

    int i = beg;
    for (; i + 8 <= end; i += 8) {
        int2 p0 = perm[i + 0], p1 = perm[i + 1], p2 = perm[i + 2], p3 = perm[i + 3];
        int2 p4 = perm[i + 4], p5 = perm[i + 5], p6 = perm[i + 6], p7 = perm[i + 7];
        float w0 = __int_as_float(p0.y), w1 = __int_as_float(p1.y);
        float w2 = __int_as_float(p2.y), w3 = __int_as_float(p3.y);
        float w4 = __int_as_float(p4.y), w5 = __int_as_float(p5.y);
        float w6 = __int_as_float(p6.y), w7 = __int_as_float(p7.y);
        ushort4 r0 = ((const ushort4*)(vb + (size_t)p0.x * D_IN))[lane];
        ushort4 r1 = ((const ushort4*)(vb + (size_t)p1.x * D_IN))[lane];
        ushort4 r2 = ((const ushort4*)(vb + (size_t)p2.x * D_IN))[lane];
        ushort4 r3 = ((const ushort4*)(vb + (size_t)p3.x * D_IN))[lane];
        ushort4 r4 = ((const ushort4*)(vb + (size_t)p4.x * D_IN))[lane];
        ushort4 r5 = ((const ushort4*)(vb + (size_t)p5.x * D_IN))[lane];
        ushort4 r6 = ((const ushort4*)(vb + (size_t)p6.x * D_IN))[lane];
        ushort4 r7 = ((const ushort4*)(vb + (size_t)p7.x * D_IN))[lane];
        a0 += w0 * bf2f(r0.x) + w1 * bf2f(r1.x) + w2 * bf2f(r2.x) + w3 * bf2f(r3.x);
        a1 += w0 * bf2f(r0.y) + w1 * bf2f(r1.y) + w2 * bf2f(r2.y) + w3 * bf2f(r3.y);
        a2 += w0 * bf2f(r0.z) + w1 * bf2f(r1.z) + w2 * bf2f(r2.z) + w3 * bf2f(r3.z);
        a3 += w0 * bf2f(r0.w) + w1 * bf2f(r1.w) + w2 * bf2f(r2.w) + w3 * bf2f(r3.w);
        c0 += w4 * bf2f(r4.x) + w5 * bf2f(r5.x) + w6 * bf2f(r6.x) + w7 * bf2f(r7.x);
        c1 += w4 * bf2f(r4.y) + w5 * bf2f(r5.y) + w6 * bf2f(r6.y) + w7 * bf2f(r7.y);
        c2 += w4 * bf2f(r4.z) + w5 * bf2f(r5.z) + w6 * bf2f(r6.z) + w7 * bf2f(r7.z);
        c3 += w4 * bf2f(r4.w) + w5 * bf2f(r5.w) + w6 * bf2f(r6.w) + w7 * bf2f(r7.w);
    }
    for (; i + 4 <= end; i += 4) {
        int2 p0 = perm[i + 0], p1 = perm[i + 1], p2 = perm[i + 2], p3 = perm[i + 3];
        float w0 = __int_as_float(p0.y), w1 = __int_as_float(p1.y);
        float w2 = __int_as_float(p2.y), w3 = __int_as_float(p3.y);
        ushort4 r0 = ((const ushort4*)(vb + (size_t)p0.x * D_IN))[lane];
        ushort4 r1 = ((const ushort4*)(vb + (size_t)p1.x * D_IN))[lane];
        ushort4 r2 = ((const ushort4*)(vb + (size_t)p2.x * D_IN))[lane];
        ushort4 r3 = ((const ushort4*)(vb + (size_t)p3.x * D_IN))[lane];
        a0 += w0 * bf2f(r0.x) + w1 * bf2f(r1.x) + w2 * bf2f(r2.x) + w3 * bf2f(r3.x);
        a1 += w0 * bf2f(r0.y) + w1 * bf2f(r1.y) + w2 * bf2f(r2.y) + w3 * bf2f(r3.y);
        a2 += w0 * bf2f(r0.z) + w1 * bf2f(r1.z) + w2 * bf2f(r2.z) + w3 * bf2f(r3.z);
        a3 += w0 * bf2f(r0.w) + w1 * bf2f(r1.w) + w2 * bf2f(r2.w) + w3 * bf2f(r3.w);
    }
    for (; i < end; ++i) {
        int2 p = perm[i];
        float w = __int_as_float(p.y);
        ushort4 r = ((const ushort4*)(vb + (size_t)p.x * D_IN))[lane];
        a0 += w * bf2f(r.x); a1 += w * bf2f(r.y);
        a2 += w * bf2f(r.z); a3 += w * bf2f(r.w);
    }
    a0 += c0; a1 += c1; a2 += c2; a3 += c3;
    float eps = eps_p[0];
    ushort4 m = ((const ushort4*)(vb + (size_t)node * D_IN))[lane];
    a0 += eps * bf2f(m.x); a1 += eps * bf2f(m.y);
    a2 += eps * bf2f(m.z); a3 += eps * bf2f(m.w);
    ((ushort4*)(aggb + (size_t)node * D_IN))[lane] =
        make_ushort4(f2bf(a0), f2bf(a1), f2bf(a2), f2bf(a3));
}

// ---------------------------------------------------------------------------
// Fused MLP, 64-row tile, 256 thr / 4 waves, reg-pipelined K-loops
// (R6-proven 59.4us; acc in AGPRs -> ~256 regs/wave -> 2 blocks/CU cap)
// ---------------------------------------------------------------------------
#define HS_IDX(row, col) ((row) * 512 + ((col) ^ (((row) & 7) << 3)))
#define AT_IDX(row, col) ((row) * 256 + ((col) ^ (((row) & 7) << 3)))

__global__ __launch_bounds__(256, 2) void mlp_kernel(
    const ushort* __restrict__ A, const ushort* __restrict__ w1p,
    const ushort* __restrict__ w2p,
    const float* __restrict__ b1, const float* __restrict__ g1, const float* __restrict__ be1,
    const float* __restrict__ b2, const float* __restrict__ g2, const float* __restrict__ be2,
    float* __restrict__ out, int N) {
    __shared__ ushort hs[32768];      // 64 KB
    __shared__ float redf[640];

    int t = threadIdx.x;
    int w = t >> 6, lane = t & 63;
    int row0 = blockIdx.x * 64;
    int fr = lane & 15, q = lane >> 4, kb = q * 8;

    // ---- stage A-tile once: 8 coalesced 1KB loads/wave, source-swizzled ----
    #pragma unroll
    for (int j = 0; j < 8; ++j) {
        int p = (w * 8 + j) * 64 + lane;
        int row = p >> 5, cbs = p & 31;
        int colblk = cbs ^ (row & 7);
        int ar = row0 + row; if (ar > N - 1) ar = N - 1;
        const ushort* gp = A + (size_t)ar * D_IN + colblk * 8;
        __builtin_amdgcn_global_load_lds(
            (const __attribute__((address_space(1))) void*)gp,
            (__attribute__((address_space(3))) void*)(&hs[(w * 8 + j) * 512]),
            16, 0, 0);
    }

    bf16x8 bfb[2][8];
    #pragma unroll
    for (int c = 0; c < 8; ++c)
        bfb[0][c] = *(const bf16x8*)(w1p + (size_t)((w * 8 + c) * 64 + lane) * 8);

    __syncthreads();

    f32x4 acc[4][8];
    #pragma unroll
    for (int m = 0; m < 4; ++m)
        #pragma unroll
        for (int c = 0; c < 8; ++c) {
            f32x4 z = {0.f, 0.f, 0.f, 0.f};
            acc[m][c] = z;
        }

    #pragma unroll
    for (int ks = 0; ks < 8; ++ks) {
        const int cur = ks & 1, nxt = cur ^ 1;
        if (ks < 7) {
            #pragma unroll
            for (int c = 0; c < 8; ++c)
                bfb[nxt][c] = *(const bf16x8*)(w1p +
                    (size_t)(((ks + 1) * 32 + w * 8 + c) * 64 + lane) * 8);
        }
        bf16x8 af[4];
        #pragma unroll
        for (int m = 0; m < 4; ++m)
            af[m] = *(const bf16x8*)&hs[AT_IDX(m * 16 + fr, ks * 32 + kb)];
        #pragma unroll
        for (int m = 0; m < 4; ++m)
            #pragma unroll
            for (int c = 0; c < 8; ++c)
                acc[m][c] = __builtin_amdgcn_mfma_f32_16x16x32_bf16(af[m], bfb[cur][c], acc[m][c], 0, 0, 0);
    }

    {
        float bi[8], gg[8], bb[8];
        #pragma unroll
        for (int c = 0; c < 8; ++c) {
            int col = w * 128 + c * 16 + fr;
            bi[c] = b1[col]; gg[c] = g1[col]; bb[c] = be1[col];
        }
        #pragma unroll
        for (int m = 0; m < 4; ++m) {
            #pragma unroll
            for (int r = 0; r < 4; ++r) {
                float s = 0.f, sq = 0.f;
                #pragma unroll
                for (int c = 0; c < 8; ++c) {
                    float x = acc[m][c][r] + bi[c];
                    acc[m][c][r] = x;
                    s += x; sq += x * x;
                }
                #pragma unroll
                for (int o = 1; o < 16; o <<= 1) {
                    s  += __shfl_xor(s, o, 64);
                    sq += __shfl_xor(sq, o, 64);
                }
                if (fr == 0) {
                    int row = m * 16 + q * 4 + r;
                    redf[row * 4 + w]       = s;
                    redf[256 + row * 4 + w] = sq;
                }
            }
        }
        __syncthreads();
        if (t < 64) {
            float s  = redf[t * 4 + 0] + redf[t * 4 + 1] + redf[t * 4 + 2] + redf[t * 4 + 3];
            float sq = redf[256 + t * 4 + 0] + redf[256 + t * 4 + 1] +
                       redf[256 + t * 4 + 2] + redf[256 + t * 4 + 3];
            float mu = s / (float)D_HID;
            float var = sq / (float)D_HID - mu * mu;
            redf[512 + t] = mu;
            redf[576 + t] = rsqrtf(var + LN_EPS);
        }
        __syncthreads();
        #pragma unroll
        for (int m = 0; m < 4; ++m) {
            #pragma unroll
            for (int r = 0; r < 4; ++r) {
                int row = m * 16 + q * 4 + r;
                float mu = redf[512 + row], rs = redf[576 + row];
                #pragma unroll
                for (int c = 0; c < 8; ++c) {
                    int col = w * 128 + c * 16 + fr;
                    float y = (acc[m][c][r] - mu) * rs * gg[c] + bb[c];
                    hs[HS_IDX(row, col)] = f2bf(fmaxf(y, 0.f));
                }
            }
        }
    }

    bf16x8 bf2b[2][4][2];
    #pragma unroll
    for (int c = 0; c < 4; ++c)
        #pragma unroll
        for (int h = 0; h < 2; ++h)
            bf2b[0][c][h] = *(const bf16x8*)(w2p +
                (size_t)(((0 + h) * 16 + w * 4 + c) * 64 + lane) * 8);

    __syncthreads();

    f32x4 acc2[4][4];
    #pragma unroll
    for (int m = 0; m < 4; ++m)
        #pragma unroll
        for (int c = 0; c < 4; ++c) {
            f32x4 z = {0.f, 0.f, 0.f, 0.f};
            acc2[m][c] = z;
        }

    #pragma unroll
    for (int s2 = 0; s2 < 8; ++s2) {
        const int cur = s2 & 1, nxt = cur ^ 1;
        if (s2 < 7) {
            #pragma unroll
            for (int c = 0; c < 4; ++c)
                #pragma unroll
                for (int h = 0; h < 2; ++h)
                    bf2b[nxt][c][h] = *(const bf16x8*)(w2p +
                        (size_t)(((2 * (s2 + 1) + h) * 16 + w * 4 + c) * 64 + lane) * 8);
        }
        bf16x8 af2[4][2];
        #pragma unroll
        for (int m = 0; m < 4; ++m)
            #pragma unroll
            for (int h = 0; h < 2; ++h)
                af2[m][h] = *(const bf16x8*)&hs[HS_IDX(m * 16 + fr, s2 * 64 + h * 32 + kb)];
        #pragma unroll
        for (int m = 0; m < 4; ++m)
            #pragma unroll
            for (int c = 0; c < 4; ++c)
                #pragma unroll
                for (int h = 0; h < 2; ++h)
                    acc2[m][c] = __builtin_amdgcn_mfma_f32_16x16x32_bf16(af2[m][h], bf2b[cur][c][h], acc2[m][c], 0, 0, 0);
    }

    {
        float bi[4], gg[4], bb[4];
        #pragma unroll
        for (int c = 0; c < 4; ++c) {
            int col = w * 64 + c * 16 + fr;
            bi[c] = b2[col]; gg[c] = g2[col]; bb[c] = be2[col];
        }
        #pragma unroll
        for (int m = 0; m < 4; ++m) {
            #pragma unroll
            for (int r = 0; r < 4; ++r) {
                float s = 0.f, sq = 0.f;
                #pragma unroll
                for (int c = 0; c < 4; ++c) {
                    float x = acc2[m][c][r] + bi[c];
                    acc2[m][c][r] = x;
                    s += x; sq += x * x;
                }
                #pragma unroll
                for (int o = 1; o < 16; o <<= 1) {
                    s  += __shfl_xor(s, o, 64);
                    sq += __shfl_xor(sq, o, 64);
                }
                if (fr == 0) {
                    int row = m * 16 + q * 4 + r;
                    redf[row * 4 + w]       = s;
                    redf[256 + row * 4 + w] = sq;
                }
            }
        }
        __syncthreads();
        if (t < 64) {
            float s  = redf[t * 4 + 0] + redf[t * 4 + 1] + redf[t * 4 + 2] + redf[t * 4 + 3];
            float sq = redf[256 + t * 4 + 0] + redf[256 + t * 4 + 1] +
                       redf[256 + t * 4 + 2] + redf[256 + t * 4 + 3];
            float mu = s / (float)D_OUT;
            float var = sq / (float)D_OUT - mu * mu;
            redf[512 + t] = mu;
            redf[576 + t] = rsqrtf(var + LN_EPS);
        }
        __syncthreads();
        #pragma unroll
        for (int m = 0; m < 4; ++m) {
            #pragma unroll
            for (int r = 0; r < 4; ++r) {
                int row = m * 16 + q * 4 + r;
                int grow = row0 + row;
                if (grow >= N) continue;
                float mu = redf[512 + row], rs = redf[576 + row];
                #pragma unroll
                for (int c = 0; c < 4; ++c) {
                    int col = w * 64 + c * 16 + fr;
                    float y = (acc2[m][c][r] - mu) * rs * gg[c] + bb[c];
                    out[(size_t)grow * D_OUT + col] = fmaxf(y, 0.f);
                }
            }
        }
    }
}

// ---------------------------------------------------------------------------
extern "C" void kernel_launch(void* const* d_in, const int* in_sizes, int n_in,
                              void* d_out, int out_size, void* d_ws, size_t ws_size,
                              hipStream_t stream) {
    const float* v     = (const float*)d_in[0];
    const float* ew    = (const float*)d_in[1];
    const float* eps   = (const float*)d_in[2];
    const float* w1    = (const float*)d_in[3];
    const float* b1    = (const float*)d_in[4];
    const float* g1    = (const float*)d_in[5];
    const float* beta1 = (const float*)d_in[6];
    const float* w2    = (const float*)d_in[7];
    const float* b2    = (const float*)d_in[8];
    const float* g2    = (const float*)d_in[9];
    const float* beta2 = (const float*)d_in[10];
    const int*   src   = (const int*)d_in[11];
    const int*   dst   = (const int*)d_in[12];

    int N = in_sizes[0] / D_IN;     // 50000
    int E = in_sizes[1];            // 800000

    float* out = (float*)d_out;

    // workspace layout (256B-aligned chunks)
    char* ws = (char*)d_ws;
    size_t off = 0;
    ushort* vb   = (ushort*)(ws + off); off += (size_t)N * D_IN * 2;            // 25.6 MB
    ushort* aggb = (ushort*)(ws + off); off += (size_t)N * D_IN * 2;            // 25.6 MB
    ushort* w1p  = (ushort*)(ws + off); off += (size_t)D_HID * D_IN * 2;        // 256 KB
    ushort* w2p  = (ushort*)(ws + off); off += (size_t)D_OUT * D_HID * 2;       // 256 KB
    int* offs     = (int*)(ws + off); off += (size_t)(N + 256) * 4;
    int* cnt      = (int*)(ws + off); off += (size_t)(N + 16) * CPAD * 4;       // 3.2 MB, zeroed
    int* bsum     = (int*)(ws + off); off += 1024;
    int* rank     = (int*)(ws + off); off += (size_t)E * 4;                     // 3.2 MB
    int2* perm    = (int2*)(ws + off); off += (size_t)E * 8;                    // 6.4 MB

    int n4v = N * (D_IN / 4);
    int bv = (n4v + 255) / 256;
    int bw = 256;                     // 65536 float4s of weights
    int be = (E + 255) / 256;
    int nb = (N + SCAN_B - 1) / SCAN_B;

    // 0) zero the padded histogram
    hipMemsetAsync(cnt, 0, (size_t)N * CPAD * 4, stream);

    // 1) prep: hist/rank first (overlap), then casts + packed weights
    prep_kernel<<<be + bv + bw, 256, 0, stream>>>(v, w1, w2, vb, w1p, w2p,
                                                  dst, rank, cnt, n4v, E, be, bv);

    // 2) CSR offsets (two-level scan, proven; strided cnt read)
    scan1_kernel<<<nb, SCAN_B, 0, stream>>>(cnt, offs, bsum, N);
    scan3_kernel<<<nb, SCAN_B, 0, stream>>>(offs, bsum, N, E, nb);

    // 3) counting-sort fill (no atomics)
    fill_kernel<<<be, 256, 0, stream>>>(src, dst, ew, rank, offs, perm, E);

    // 4) aggregate (bf16 gather), high-TLP standalone
    aggregate_kernel<<<(N + 3) / 4, 256, 0, stream>>>(vb, eps, offs, perm, aggb, N);

    // 5) fused MLP (R6-proven 64-row / 256-thread)
    int mblocks = (N + 63) / 64;
    mlp_kernel<<<mblocks, 256, 0, stream>>>(aggb, w1p, w2p,
                                            b1, g1, beta1, b2, g2, beta2, out, N);
}